// Round 5
// baseline (246.524 us; speedup 1.0000x reference)
//
#include <hip/hip_runtime.h>

#define KK 32
#define HH 6
#define OO 31
#define EPS 1e-6f
#define MIX_DW (256 * OO)          // 7936 dwords = 31744 B dynamic LDS

typedef __attribute__((ext_vector_type(8))) short short8;
typedef __attribute__((ext_vector_type(4))) float f32x4;

__device__ __forceinline__ unsigned short f2b(float f) {
    union { float f; unsigned int u; } v; v.f = f;
    unsigned int u = v.u;
    u += 0x7fffu + ((u >> 16) & 1u);   // RNE to bf16
    return (unsigned short)(u >> 16);
}
__device__ __forceinline__ unsigned int pack2(float a, float b) {
    return (unsigned int)f2b(a) | ((unsigned int)f2b(b) << 16);
}

// mix[P x 31] = Coef[P x 192] * W'[192 x 31] via bf16 MFMA, fp32 accumulate.
// kh ordering is h-major (kh = h*32 + k) so each 16x16x32 K-step is one h.
// A-frag: lane(m=l&15, q=l>>4) holds Coef[point m][h*32 + q*8 + j] -- computed
// in-register by that very lane (no LDS staging for A at all).
// B-frag: W' bf16 in LDS, layout Wb[h][q][n][8k] -> aligned b128, n..n+8
// alias banks 2-way (free). D: row=(l>>4)*4+r (point), col=l&15(+16) (output).
// Epilogue: D -> LDS mix tile (union with Wb, after barrier), then coalesced
// float4 mlp*mix like R3 (WRITE_SIZE == output exactly).
__global__ __launch_bounds__(256, 4) void hermite_mfma_kernel(
    const float* __restrict__ mlp,     // [P, OO]
    const float* __restrict__ cd,      // [P, KK, 2]
    const float* __restrict__ sigmas,  // [KK]
    const float* __restrict__ gw,      // [P, KK]
    const float* __restrict__ W,       // [KK, HH, OO]
    float* __restrict__ out,           // [P, OO]
    int P)
{
    extern __shared__ char smem_raw[];
    unsigned short* Wb = (unsigned short*)smem_raw;   // [H][4][32][8] bf16 = 12 KB
    float* smix = (float*)smem_raw;                   // epilogue mix tile, 31.75 KB

    const int tid = threadIdx.x;

    // Stage W -> LDS bf16: Wb[((h*4+q)*32+n)*8+j] = W[(q*8+j)*H*O + h*O + n], n=31 -> 0
    for (int idx = tid; idx < HH * 4 * 32 * 8; idx += 256) {
        int j = idx & 7;
        int n = (idx >> 3) & 31;
        int q = (idx >> 8) & 3;
        int h = idx >> 10;
        int k = q * 8 + j;
        float v = (n < OO) ? W[k * (HH * OO) + h * OO + n] : 0.0f;
        Wb[idx] = f2b(v);
    }
    __syncthreads();

    const int l  = tid & 63;   // lane
    const int w  = tid >> 6;   // wave 0..3
    const int m  = l & 15;     // point-in-tile / output col
    const int kq = l >> 4;     // k-quad 0..3

    // Per-lane 1/s2, 1/s4 for this lane's fixed 8 k's (kq*8..kq*8+7)
    float i2[8], i4[8];
#pragma unroll
    for (int j = 0; j < 8; ++j) {
        float s = sigmas[kq * 8 + j];
        float s2 = s * s;
        i2[j] = 1.0f / (s2 + EPS);
        i4[j] = 1.0f / (s2 * s2 + EPS);
    }

    f32x4 acc[4][2];
#pragma unroll
    for (int t = 0; t < 4; ++t) { acc[t][0] = (f32x4)0.0f; acc[t][1] = (f32x4)0.0f; }

    const int blockBase = blockIdx.x * 256;
    const short8* wb8 = (const short8*)Wb;

#pragma unroll
    for (int t = 0; t < 4; ++t) {
        const int p = blockBase + w * 64 + t * 16 + m;
        // Full-sector bursts (R2 lesson): cd 64 B/lane, gw 32 B/lane
        const float4* cdp = (const float4*)cd + (size_t)p * 16 + kq * 4;
        const float4* gwp = (const float4*)gw + (size_t)p * 8 + kq * 2;
        float4 c0 = cdp[0], c1 = cdp[1], c2 = cdp[2], c3 = cdp[3];
        float4 g01 = gwp[0], g23 = gwp[1];

        float cf[16] = {c0.x,c0.y,c0.z,c0.w, c1.x,c1.y,c1.z,c1.w,
                        c2.x,c2.y,c2.z,c2.w, c3.x,c3.y,c3.z,c3.w};
        float gf[8]  = {g01.x,g01.y,g01.z,g01.w, g23.x,g23.y,g23.z,g23.w};

        unsigned int us[6][4];   // packed bf16x2 coeffs: us[h][jj] = (k=2jj, k=2jj+1)
#pragma unroll
        for (int jj = 0; jj < 4; ++jj) {
            float dv[2][6];
#pragma unroll
            for (int e = 0; e < 2; ++e) {
                int j = 2 * jj + e;
                float dx = cf[2 * j], dy = cf[2 * j + 1], g = gf[j];
                float t2 = g * i2[j], t4 = g * i4[j];
                float dxt4 = dx * t4, dyt4 = dy * t4;
                dv[e][0] = g;                     // (0,0)
                dv[e][1] = -dy * t2;              // (0,1)
                dv[e][2] = -dx * t2;              // (1,0)
                dv[e][3] = fmaf(dy, dyt4, -t2);   // (0,2)
                dv[e][4] = dx * dyt4;             // (1,1)
                dv[e][5] = fmaf(dx, dxt4, -t2);   // (2,0)
            }
#pragma unroll
            for (int h = 0; h < 6; ++h) us[h][jj] = pack2(dv[0][h], dv[1][h]);
        }

#pragma unroll
        for (int h = 0; h < 6; ++h) {
            union { unsigned int u[4]; short8 s; } av;
            av.u[0] = us[h][0]; av.u[1] = us[h][1];
            av.u[2] = us[h][2]; av.u[3] = us[h][3];
            short8 b0 = wb8[(h * 4 + kq) * 32 + m];        // N-half 0
            short8 b1 = wb8[(h * 4 + kq) * 32 + m + 16];   // N-half 1
            acc[t][0] = __builtin_amdgcn_mfma_f32_16x16x32_bf16(av.s, b0, acc[t][0], 0, 0, 0);
            acc[t][1] = __builtin_amdgcn_mfma_f32_16x16x32_bf16(av.s, b1, acc[t][1], 0, 0, 0);
        }
    }

    __syncthreads();   // all waves done reading Wb; mix region may overwrite it

    // D-frags -> mix tile: lane holds rows kq*4+r, cols m and m+16
#pragma unroll
    for (int t = 0; t < 4; ++t) {
#pragma unroll
        for (int nh = 0; nh < 2; ++nh) {
            int o = m + 16 * nh;
            if (o < OO) {
#pragma unroll
                for (int r = 0; r < 4; ++r) {
                    int pl = w * 64 + t * 16 + kq * 4 + r;
                    smix[pl * OO + o] = acc[t][nh][r];
                }
            }
        }
    }
    __syncthreads();

    // Coalesced epilogue over the block's contiguous 7936-dword range
    {
        const size_t blk_dw = (size_t)blockIdx.x * MIX_DW;
        const float4* __restrict__ mlpv = (const float4*)(mlp + blk_dw);
        float4* __restrict__ outv = (float4*)(out + blk_dw);
        const float4* mixv = (const float4*)smix;
        for (int j2 = tid; j2 < MIX_DW / 4; j2 += 256) {
            float4 mm = mlpv[j2];
            float4 xx = mixv[j2];
            float4 rr;
            rr.x = mm.x * xx.x;
            rr.y = mm.y * xx.y;
            rr.z = mm.z * xx.z;
            rr.w = mm.w * xx.w;
            outv[j2] = rr;
        }
    }
}

extern "C" void kernel_launch(void* const* d_in, const int* in_sizes, int n_in,
                              void* d_out, int out_size, void* d_ws, size_t ws_size,
                              hipStream_t stream) {
    const float* mlp    = (const float*)d_in[0]; // [B,N,O]
    const float* cd     = (const float*)d_in[1]; // [B,N,K,2]
    const float* sigmas = (const float*)d_in[2]; // [K]
    const float* gw     = (const float*)d_in[3]; // [B,N,K]
    const float* W      = (const float*)d_in[4]; // [K,H,O]
    float* out          = (float*)d_out;

    const int P = in_sizes[3] / KK;      // B*N = 262144 (exact multiple of 256)
    const int grid = P / 256;            // 1024 blocks
    const size_t lds_bytes = MIX_DW * 4; // 31744 B

    hermite_mfma_kernel<<<grid, 256, lds_bytes, stream>>>(mlp, cd, sigmas, gw, W, out, P);
}